// Round 4
// baseline (151.860 us; speedup 1.0000x reference)
//
#include <hip/hip_runtime.h>
#include <hip/hip_bf16.h>
#include <math.h>

#define BB 4
#define VV 1024
#define HH 128
#define H2 64
#define EE 523776               // V*(V-1)/2
#define BE (BB * EE)            // 2095104
#define TPB (EE / 16)           // 32736 tiles per batch (even)
#define NTILES (BE / 16)        // 130944
#define NPAIR (NTILES / 2)      // 65472
#define NTHR 256
#define NBLK 1024

typedef __attribute__((ext_vector_type(8))) short bf16x8;
typedef __attribute__((ext_vector_type(4))) float f32x4;

__device__ __forceinline__ short f2bf(float f) {
    __hip_bfloat16 h = __float2bfloat16(f);
    return *reinterpret_cast<short*>(&h);
}

// ---------------------------------------------------------------------------
// Round 4: 2-tile ILP per wave + launch_bounds(256,2) so ALL weight fragments
// stay VGPR-resident (R3's VGPR=84 < 128 persistent-need proved the compiler
// was shedding weights into the loop). Two adjacent 16-edge tiles per
// iteration give two independent dep chains; their MFMA/VALU phases overlap.
// Same fused layout trick as R3: L1 A-rows permuted so L1 C/D output IS the
// L2 B-fragment (no LDS, no barriers anywhere).
// ---------------------------------------------------------------------------
__global__ __launch_bounds__(NTHR, 2) void edge_mlp_mfma3(
    const float* __restrict__ vertices,  // [4,1024,3]
    const float* __restrict__ W1,        // [6,128]
    const float* __restrict__ b1,        // [128]
    const float* __restrict__ W2,        // [128,64]
    const float* __restrict__ b2,        // [64]
    const float* __restrict__ W3,        // [64]
    const float* __restrict__ b3,        // [1]
    float* __restrict__ out)             // [BE probs][2*EE indices-as-float]
{
    const int lane = threadIdx.x & 63;
    const int col  = lane & 15;          // edge slot (N dim everywhere)
    const int u    = lane >> 4;
    const int wid  = threadIdx.x >> 6;

    const f32x4 zero4 = {0.f, 0.f, 0.f, 0.f};

    // ---- persistent weight fragments (VGPRs) ----
    // L1: A1[p][q][r] = W1pad[k=8u+r][h], h = 32p + 8*(col>>2) + 4q + (col&3)
    bf16x8 A1[4][2];
#pragma unroll
    for (int p = 0; p < 4; ++p)
#pragma unroll
        for (int q = 0; q < 2; ++q) {
            const int h = 32 * p + 8 * (col >> 2) + 4 * q + (col & 3);
#pragma unroll
            for (int r = 0; r < 8; ++r) {
                const int k = 8 * u + r;
                float w = 0.0f;
                if (k < 6)       w = W1[k * HH + h];
                else if (k == 6) w = b1[h];
                A1[p][q][r] = f2bf(w);
            }
        }

    // L2: A2[mt][p][r] = W2[h=32p+8u+r][n2=16mt+col]
    bf16x8 A2[4][4];
#pragma unroll
    for (int mt = 0; mt < 4; ++mt)
#pragma unroll
        for (int p = 0; p < 4; ++p) {
            const int n2 = 16 * mt + col;
#pragma unroll
            for (int r = 0; r < 8; ++r) {
                const int h = 32 * p + 8 * u + r;
                A2[mt][p][r] = f2bf(W2[h * H2 + n2]);
            }
        }

    // epilogue constants; b2 enters as the L2 accumulator init
    f32x4 cinit[4];
    float w3c[16];
#pragma unroll
    for (int mt = 0; mt < 4; ++mt)
#pragma unroll
        for (int q = 0; q < 4; ++q) {
            const int n2 = 16 * mt + 4 * u + q;
            cinit[mt][q]    = b2[n2];
            w3c[mt * 4 + q] = W3[n2];
        }
    const float b3v = b3[0];

    const int gw = blockIdx.x * 4 + wid;

    for (int pt = gw; pt < NPAIR; pt += NBLK * 4) {
        const int tt0 = pt * 2;               // tiles tt0, tt0+1 share batch b
        const int b   = tt0 / TPB;
        const int e00 = (tt0 - b * TPB) * 16;

        int iv[2], jv[2];
        bf16x8 bfv[2];

        // ---- decode + feature build for both tiles ----
#pragma unroll
        for (int s = 0; s < 2; ++s) {
            const int e = e00 + s * 16 + col;
            const int rr = EE - 1 - e;
            const float sq = sqrtf((float)(8 * rr + 1));
            int m = (int)(0.5f * (sq - 1.0f));
            if ((m + 1) * (m + 2) / 2 <= rr) ++m;
            if (m * (m + 1) / 2 > rr) --m;
            const int pp = rr - m * (m + 1) / 2;
            iv[s] = VV - 2 - m;
            jv[s] = VV - 1 - pp;

            bf16x8 bf = {0, 0, 0, 0, 0, 0, 0, 0};
            if (u == 0) {
                const float* pvi = vertices + (b * VV + iv[s]) * 3;
                const float* pvj = vertices + (b * VV + jv[s]) * 3;
                bf[0] = f2bf(pvi[0]); bf[1] = f2bf(pvi[1]); bf[2] = f2bf(pvi[2]);
                bf[3] = f2bf(pvj[0]); bf[4] = f2bf(pvj[1]); bf[5] = f2bf(pvj[2]);
                bf[6] = f2bf(1.0f);                       // k=6 carries b1
            }
            bfv[s] = bf;
        }

        f32x4 d2[2][4];
#pragma unroll
        for (int s = 0; s < 2; ++s)
#pragma unroll
            for (int mt = 0; mt < 4; ++mt) d2[s][mt] = cinit[mt];

        // ---- fused L1 -> pack -> L2, both tiles interleaved ----
#pragma unroll
        for (int p = 0; p < 4; ++p) {
#pragma unroll
            for (int s = 0; s < 2; ++s) {
                f32x4 dA = __builtin_amdgcn_mfma_f32_16x16x32_bf16(A1[p][0], bfv[s], zero4, 0, 0, 0);
                f32x4 dB = __builtin_amdgcn_mfma_f32_16x16x32_bf16(A1[p][1], bfv[s], zero4, 0, 0, 0);
                bf16x8 Bh;
                Bh[0] = f2bf(fmaxf(dA[0], 0.f)); Bh[1] = f2bf(fmaxf(dA[1], 0.f));
                Bh[2] = f2bf(fmaxf(dA[2], 0.f)); Bh[3] = f2bf(fmaxf(dA[3], 0.f));
                Bh[4] = f2bf(fmaxf(dB[0], 0.f)); Bh[5] = f2bf(fmaxf(dB[1], 0.f));
                Bh[6] = f2bf(fmaxf(dB[2], 0.f)); Bh[7] = f2bf(fmaxf(dB[3], 0.f));
                d2[s][0] = __builtin_amdgcn_mfma_f32_16x16x32_bf16(A2[0][p], Bh, d2[s][0], 0, 0, 0);
                d2[s][1] = __builtin_amdgcn_mfma_f32_16x16x32_bf16(A2[1][p], Bh, d2[s][1], 0, 0, 0);
                d2[s][2] = __builtin_amdgcn_mfma_f32_16x16x32_bf16(A2[2][p], Bh, d2[s][2], 0, 0, 0);
                d2[s][3] = __builtin_amdgcn_mfma_f32_16x16x32_bf16(A2[3][p], Bh, d2[s][3], 0, 0, 0);
            }
        }

        // ---- layer 3 + sigmoid + store, both tiles ----
#pragma unroll
        for (int s = 0; s < 2; ++s) {
            float acc = 0.f;
#pragma unroll
            for (int mt = 0; mt < 4; ++mt)
#pragma unroll
                for (int q = 0; q < 4; ++q)
                    acc = fmaf(fmaxf(d2[s][mt][q], 0.f), w3c[mt * 4 + q], acc);

            acc += __shfl_xor(acc, 16);
            acc += __shfl_xor(acc, 32);

            if (u == 0) {
                const float x = acc + b3v;
                const float prob = __builtin_amdgcn_rcpf(1.0f + __expf(-x));
                out[(tt0 + s) * 16 + col] = prob;
                if (b == 0) {
                    const int e = e00 + s * 16 + col;
                    *(float2*)(&out[BE + 2 * e]) = make_float2((float)iv[s], (float)jv[s]);
                }
            }
        }
    }
}

extern "C" void kernel_launch(void* const* d_in, const int* in_sizes, int n_in,
                              void* d_out, int out_size, void* d_ws, size_t ws_size,
                              hipStream_t stream) {
    const float* vertices = (const float*)d_in[0];
    const float* W1 = (const float*)d_in[1];
    const float* b1 = (const float*)d_in[2];
    const float* W2 = (const float*)d_in[3];
    const float* b2 = (const float*)d_in[4];
    const float* W3 = (const float*)d_in[5];
    const float* b3 = (const float*)d_in[6];
    float* out = (float*)d_out;

    edge_mlp_mfma3<<<NBLK, NTHR, 0, stream>>>(vertices, W1, b1, W2, b2, W3, b3, out);
}